// Round 2
// baseline (204.251 us; speedup 1.0000x reference)
//
#include <hip/hip_runtime.h>
#include <stdint.h>

#define NTOK 65536
#define G 4
#define K 1024
#define C 64
#define GC 256
#define R 4                            // 16-row tiles per wave -> 64 rows/wave
#define HALF_CODES 512                 // K-split: codes per block
#define HALF_HALVES (HALF_CODES * C)   // 32768 halves = 64 KB LDS
#define EMB16_BYTES (G * K * C * 2)    // 512 KB in d_ws
#define ROWS_PER_BLOCK 512             // 8 waves * 64 rows

typedef _Float16 half8 __attribute__((ext_vector_type(8)));
typedef float floatx4 __attribute__((ext_vector_type(4)));
typedef unsigned int uintx4 __attribute__((ext_vector_type(4)));

__device__ __forceinline__ void gload_lds16(const _Float16* g, _Float16* l) {
    __builtin_amdgcn_global_load_lds(
        (const __attribute__((address_space(1))) uint32_t*)g,
        (__attribute__((address_space(3))) uint32_t*)l, 16, 0, 0);
}

// Negated f16 codebook in d_ws, pre-swizzled into MFMA A-fragment order
// (same layout as before: halves off = ktpos*1024 + s*512 + lane*8, code =
// ktpos*16 + (lane&15), halves h = s*32 + (lane>>4)*8). Also inits the
// packed-argmin workspace to 0xFFFFFFFF and zeroes the loss slot.
__global__ __launch_bounds__(256)
void vq_prep(const float* __restrict__ emb, _Float16* __restrict__ emb16,
             unsigned int* __restrict__ wsbest, float* __restrict__ out) {
    int gid   = blockIdx.x * 256 + threadIdx.x;   // 0..32767
    int lane  = gid & 63;
    int s     = (gid >> 6) & 1;
    int kt    = (gid >> 7) & 7;
    int chunk = (gid >> 10) & 7;
    int g     = gid >> 13;
    int code  = chunk * 128 + kt * 16 + (lane & 15);
    int q     = lane >> 4;
    int h     = s * 32 + q * 8;
    const float* src = emb + ((size_t)(g * K + code)) * C + h;
    floatx4 a = *(const floatx4*)src;
    floatx4 b = *(const floatx4*)(src + 4);
    half8 o;
    o[0] = (_Float16)(-a[0]); o[1] = (_Float16)(-a[1]);
    o[2] = (_Float16)(-a[2]); o[3] = (_Float16)(-a[3]);
    o[4] = (_Float16)(-b[0]); o[5] = (_Float16)(-b[1]);
    o[6] = (_Float16)(-b[2]); o[7] = (_Float16)(-b[3]);
    *(half8*)(emb16 + (size_t)gid * 8) = o;

    uintx4 inf = {0xFFFFFFFFu, 0xFFFFFFFFu, 0xFFFFFFFFu, 0xFFFFFFFFu};
    uintx4* wb = (uintx4*)wsbest;                 // 65536 uintx4 total
    wb[gid * 2 + 0] = inf;
    wb[gid * 2 + 1] = inf;
    if (gid == 0) out[(size_t)NTOK * GC] = 0.0f;  // loss slot
}

// Main: each block owns (g, K-half kh, 512 rows). Half-codebook resident in
// LDS (64 KB), barrier-free K-loop with depth-2 ds_read prefetch, packed
// (score,code) argmin combined across kh via u32 atomicMin.
__global__ __launch_bounds__(512, 4)
void vq_main(const float* __restrict__ z, const _Float16* __restrict__ emb16,
             unsigned int* __restrict__ wsbest) {
    __shared__ alignas(16) _Float16 E[HALF_HALVES];   // exactly 64 KB

    const int g    = blockIdx.x & 3;
    const int kh   = (blockIdx.x >> 2) & 1;
    const int nb   = blockIdx.x >> 3;                 // 0..127
    const int tid  = threadIdx.x;
    const int wave = tid >> 6;
    const int lane = tid & 63;
    const int q    = lane >> 4;
    const int lr   = lane & 15;
    const int n0   = nb * ROWS_PER_BLOCK + wave * 64;

    // stage half-codebook: 4096 16-B units, 8 per thread (lane-linear dest)
    const _Float16* src = emb16 + (size_t)g * (K * C) + (size_t)kh * HALF_HALVES;
#pragma unroll
    for (int i = 0; i < 8; ++i) {
        const int seg = i * 512 + tid;
        gload_lds16(src + seg * 8, &E[seg * 8]);
    }

    // z fragments: 4 row-tiles x 2 k-steps, f32 -> f16 (NOT negated)
    half8 zf[R][2];
#pragma unroll
    for (int r = 0; r < R; ++r) {
        const float* zp = z + (size_t)(n0 + r * 16 + lr) * GC + g * C + q * 8;
#pragma unroll
        for (int s = 0; s < 2; ++s) {
            floatx4 a = *(const floatx4*)(zp + s * 32);
            floatx4 b = *(const floatx4*)(zp + s * 32 + 4);
            half8 h;
            h[0] = (_Float16)a[0]; h[1] = (_Float16)a[1];
            h[2] = (_Float16)a[2]; h[3] = (_Float16)a[3];
            h[4] = (_Float16)b[0]; h[5] = (_Float16)b[1];
            h[6] = (_Float16)b[2]; h[7] = (_Float16)b[3];
            zf[r][s] = h;
        }
    }

    __syncthreads();   // codebook staged (only barrier in the kernel)

    float best[R];
#pragma unroll
    for (int r = 0; r < R; ++r) best[r] = 3.4e38f;
    int vki[4];
#pragma unroll
    for (int j = 0; j < 4; ++j) vki[j] = kh * HALF_CODES + q * 4 + j;

    const floatx4 BIAS = {0.5f, 0.5f, 0.5f, 0.5f};

    auto ldE = [&](int kt2, int s) -> half8 {
        return *(const half8*)(E + kt2 * 1024 + s * 512 + lane * 8);
    };
    auto body = [&](half8 a0, half8 a1) {
#pragma unroll
        for (int r = 0; r < R; ++r) {
            floatx4 acc = __builtin_amdgcn_mfma_f32_16x16x32_f16(a0, zf[r][0], BIAS, 0, 0, 0);
            acc = __builtin_amdgcn_mfma_f32_16x16x32_f16(a1, zf[r][1], acc, 0, 0, 0);
            uint32_t p0 = (__float_as_uint(acc[0]) & 0xFFFFFC00u) | (uint32_t)vki[0];
            uint32_t p1 = (__float_as_uint(acc[1]) & 0xFFFFFC00u) | (uint32_t)vki[1];
            uint32_t p2 = (__float_as_uint(acc[2]) & 0xFFFFFC00u) | (uint32_t)vki[2];
            uint32_t p3 = (__float_as_uint(acc[3]) & 0xFFFFFC00u) | (uint32_t)vki[3];
            float t = fminf(fminf(__uint_as_float(p0), __uint_as_float(p1)),
                            __uint_as_float(p2));
            best[r] = fminf(fminf(t, __uint_as_float(p3)), best[r]);
        }
#pragma unroll
        for (int j = 0; j < 4; ++j) vki[j] += 16;
    };

    // barrier-free K-loop over 32 kt-tiles, depth-2 prefetch, named regs
    half8 p0 = ldE(0, 0), p1 = ldE(0, 1);
    half8 q0 = ldE(1, 0), q1 = ldE(1, 1);
#pragma unroll 1
    for (int kt2 = 0; kt2 < 30; kt2 += 2) {
        half8 r0 = ldE(kt2 + 2, 0), r1 = ldE(kt2 + 2, 1);
        half8 s0 = ldE(kt2 + 3, 0), s1 = ldE(kt2 + 3, 1);
        body(p0, p1);
        body(q0, q1);
        p0 = r0; p1 = r1; q0 = s0; q1 = s1;
    }
    body(p0, p1);
    body(q0, q1);

    // wave reduce across q, then device-scope packed atomicMin (u32 compare ==
    // lexicographic (score, code) since scores are positive)
#pragma unroll
    for (int r = 0; r < R; ++r) {
        float bv = best[r];
        bv = fminf(bv, __shfl_xor(bv, 16, 64));
        bv = fminf(bv, __shfl_xor(bv, 32, 64));
        if (lane < 16)
            atomicMin(wsbest + (unsigned int)(n0 + r * 16 + lr) * G + g,
                      __float_as_uint(bv));
    }
}

// Epilogue: one thread per (row, g): gather winning code (f32), write out,
// accumulate loss.
__global__ __launch_bounds__(256)
void vq_epi(const float* __restrict__ z, const float* __restrict__ emb,
            const unsigned int* __restrict__ wsbest, float* __restrict__ out) {
    __shared__ float wl[4];
    const int gidx = blockIdx.x * 256 + threadIdx.x;   // 0..262143
    const int row  = gidx >> 2;
    const int g    = gidx & 3;
    const unsigned int bv = wsbest[gidx];              // layout row*4+g
    const int ki = (int)(bv & 1023u);
    const float* ep = emb + ((size_t)(g * K + ki)) * C;
    const float* zp = z + (size_t)row * GC + g * C;
    float*       op = out + (size_t)row * GC + g * C;
    float lsum = 0.0f;
#pragma unroll
    for (int u = 0; u < 16; ++u) {
        floatx4 e  = *(const floatx4*)(ep + u * 4);
        floatx4 zz = *(const floatx4*)(zp + u * 4);
        *(floatx4*)(op + u * 4) = e;
        floatx4 d = e - zz;
        lsum += d[0] * d[0] + d[1] * d[1] + d[2] * d[2] + d[3] * d[3];
    }
#pragma unroll
    for (int off = 1; off < 64; off <<= 1) lsum += __shfl_xor(lsum, off, 64);
    const int wave = threadIdx.x >> 6;
    if ((threadIdx.x & 63) == 0) wl[wave] = lsum;
    __syncthreads();
    if (threadIdx.x == 0)
        unsafeAtomicAdd(&out[(size_t)NTOK * GC],
                        (wl[0] + wl[1] + wl[2] + wl[3]) *
                        (1.5f / ((float)NTOK * (float)GC)));
}

extern "C" void kernel_launch(void* const* d_in, const int* in_sizes, int n_in,
                              void* d_out, int out_size, void* d_ws, size_t ws_size,
                              hipStream_t stream) {
    const float* z   = (const float*)d_in[0];
    const float* emb = (const float*)d_in[1];
    float* out = (float*)d_out;
    _Float16* emb16 = (_Float16*)d_ws;
    unsigned int* wsbest = (unsigned int*)((char*)d_ws + EMB16_BYTES);  // 1 MB

    vq_prep<<<dim3(128), dim3(256), 0, stream>>>(emb, emb16, wsbest, out);
    vq_main<<<dim3((NTOK / ROWS_PER_BLOCK) * G * 2), dim3(512), 0, stream>>>(z, emb16, wsbest);
    vq_epi<<<dim3(NTOK * G / 256), dim3(256), 0, stream>>>(z, emb, wsbest, out);
}